// Round 1
// baseline (97.882 us; speedup 1.0000x reference)
//
#include <hip/hip_runtime.h>

namespace {

constexpr int kN  = 8;
constexpr int kC  = 512;
constexpr int kSP = 64 * 64;          // 4096 spatial elems per channel
constexpr int kOC = 256;              // output channels
constexpr int kVec = 4;               // float4
constexpr int kSPV = kSP / kVec;      // 1024 float4 slots per channel
constexpr int kChunk = 8;             // output channels per thread
constexpr int kNChunk = kOC / kChunk; // 32 chunks

__device__ __forceinline__ float4 vmax4(const float4 a, const float4 b) {
    return make_float4(fmaxf(a.x, b.x), fmaxf(a.y, b.y),
                       fmaxf(a.z, b.z), fmaxf(a.w, b.w));
}

// p[j] = max(xp[2j], xp[2j+1]); padded channel cp -> input channel c = cp - 3.
// Zero pads participate in the max, so out-of-range channels contribute 0.0f.
template <bool CHECKED>
__device__ __forceinline__ float4 load_pair(const float4* __restrict__ xb, int j) {
    const int c0 = 2 * j - 3;
    const int c1 = 2 * j - 2;
    const float4 z = make_float4(0.f, 0.f, 0.f, 0.f);
    float4 a = (!CHECKED || (c0 >= 0 && c0 < kC)) ? xb[(size_t)c0 * kSPV] : z;
    float4 b = (!CHECKED || (c1 >= 0 && c1 < kC)) ? xb[(size_t)c1 * kSPV] : z;
    return vmax4(a, b);
}

template <bool CHECKED>
__device__ __forceinline__ void run_chunk(const float4* __restrict__ xb,
                                          float4* __restrict__ ob, int o0) {
    float4 p0 = load_pair<CHECKED>(xb, o0);
    float4 p1 = load_pair<CHECKED>(xb, o0 + 1);
#pragma unroll
    for (int i = 0; i < kChunk; ++i) {
        const int o = o0 + i;
        const float4 p2 = load_pair<CHECKED>(xb, o + 2);
        ob[(size_t)o * kSPV] = vmax4(vmax4(p0, p1), p2);
        p0 = p1;
        p1 = p2;
    }
}

__global__ __launch_bounds__(256) void maxchpool_kernel(const float* __restrict__ x,
                                                        float* __restrict__ out) {
    const int tid = blockIdx.x * blockDim.x + threadIdx.x;
    const int sp    = tid & (kSPV - 1);          // fastest: coalesced float4
    const int chunk = (tid >> 10) & (kNChunk - 1); // wave-uniform
    const int n     = tid >> 15;                   // wave-uniform

    const float4* xb = reinterpret_cast<const float4*>(x + (size_t)n * kC * kSP) + sp;
    float4*       ob = reinterpret_cast<float4*>(out + (size_t)n * kOC * kSP) + sp;
    const int o0 = chunk * kChunk;

    // Only the first and last chunks can touch the zero padding.
    if (chunk == 0 || chunk == kNChunk - 1) {
        run_chunk<true>(xb, ob, o0);
    } else {
        run_chunk<false>(xb, ob, o0);
    }
}

}  // namespace

extern "C" void kernel_launch(void* const* d_in, const int* in_sizes, int n_in,
                              void* d_out, int out_size, void* d_ws, size_t ws_size,
                              hipStream_t stream) {
    const float* x = (const float*)d_in[0];
    float* out = (float*)d_out;

    constexpr int kTotalThreads = kN * kSPV * kNChunk;  // 262144
    const dim3 block(256);
    const dim3 grid(kTotalThreads / 256);               // 1024 blocks
    hipLaunchKernelGGL(maxchpool_kernel, grid, block, 0, stream, x, out);
}